// Round 1
// baseline (45876.801 us; speedup 1.0000x reference)
//
#include <hip/hip_runtime.h>
#include <math.h>

#define NN 512      // nodes
#define NB 256      // batch
#define NT 200      // time steps
#define ROWS 16     // batch rows per team
#define COLS 32     // output cols per block
#define NTEAM 16    // blocks per team (column groups)
#define TPB 128

// ws layout in floats
#define WS_WM  0                       // Wm = W1*mask  [512*512]
#define WS_H   (NN*NN)                 // h buffer      [256*512]
#define WS_YS  (WS_H + NB*NN)          // y_stage       [256*512]
#define WS_CNT (WS_YS + NB*NN)         // 16 team counters, stride 32 u32

#define FMA4(acc, u, v) do { \
  acc.x = fmaf(u.x, v.x, acc.x); acc.y = fmaf(u.y, v.y, acc.y); \
  acc.z = fmaf(u.z, v.z, acc.z); acc.w = fmaf(u.w, v.w, acc.w); } while (0)

__global__ __launch_bounds__(256)
void k_init(const float* __restrict__ W1, const float* __restrict__ mask,
            const float* __restrict__ x_init, float* __restrict__ ws,
            float* __restrict__ out) {
  int gt = blockIdx.x * 256 + threadIdx.x;
  int stride = gridDim.x * 256;
  for (int i = gt; i < NN * NN; i += stride) ws[WS_WM + i] = W1[i] * mask[i];
  for (int i = gt; i < NB * NN; i += stride) {
    int r = i >> 9, n = i & (NN - 1);
    out[((size_t)r * NT) * NN + n] = x_init[i];   // traj[:,0,:] = x_init
  }
  if (gt < 16 * 32) ((unsigned*)(ws + WS_CNT))[gt] = 0u;
}

__device__ __forceinline__ void team_release(unsigned* cnt) {
  __syncthreads();                 // all block stores drained (vmcnt 0 before barrier)
  if (threadIdx.x == 0) {
    __threadfence();               // release: write back L2 so other XCDs can see
    atomicAdd(cnt, 1u);            // device-scope, lands at MALL
  }
}

__device__ __forceinline__ void team_wait(unsigned* cnt, unsigned target) {
  if (threadIdx.x == 0) {
    while (__hip_atomic_load(cnt, __ATOMIC_RELAXED, __HIP_MEMORY_SCOPE_AGENT) < target)
      __builtin_amdgcn_s_sleep(2);
  }
  __syncthreads();
  __threadfence();                 // acquire: invalidate L1/L2 so reads miss to MALL
}

// C tile [2x2] = y[rows ra,rb] . W^T[cols ca,cb], K=512 as 128 float4 granules.
// LDS layouts: yf[g*16 + row], wf[g*32 + col]  (granule-major, conflict-light)
__device__ __forceinline__ void gemm_tile(const float4* __restrict__ yf,
                                          const float4* __restrict__ wf,
                                          int ra, int rb, int ca, int cb,
                                          float& o00, float& o01, float& o10, float& o11) {
  float4 a00 = make_float4(0.f,0.f,0.f,0.f), a01 = make_float4(0.f,0.f,0.f,0.f);
  float4 a10 = make_float4(0.f,0.f,0.f,0.f), a11 = make_float4(0.f,0.f,0.f,0.f);
  const float4* ypa = yf + ra;
  const float4* ypb = yf + rb;
  const float4* wpa = wf + ca;
  const float4* wpb = wf + cb;
#pragma unroll 8
  for (int g = 0; g < 128; ++g) {
    float4 y0 = ypa[g * 16];
    float4 y1 = ypb[g * 16];
    float4 w0 = wpa[g * 32];
    float4 w1 = wpb[g * 32];
    FMA4(a00, y0, w0); FMA4(a01, y0, w1);
    FMA4(a10, y1, w0); FMA4(a11, y1, w1);
  }
  o00 = (a00.x + a00.y) + (a00.z + a00.w);
  o01 = (a01.x + a01.y) + (a01.z + a01.w);
  o10 = (a10.x + a10.y) + (a10.z + a10.w);
  o11 = (a11.x + a11.y) + (a11.z + a11.w);
}

__global__ __launch_bounds__(TPB)
void k_ode(const float* __restrict__ tspan,
           const float* __restrict__ W2g,
           const float* __restrict__ b1,
           const float* __restrict__ b2,
           float* __restrict__ ws,
           float* __restrict__ out) {
  extern __shared__ float lds[];
  float4* w1f = (float4*)lds;                 // [128][32] float4
  float4* w2f = (float4*)(lds + 32 * NN);     // [128][32] float4
  float4* yf  = (float4*)(lds + 64 * NN);     // [128][16] float4

  const int bid = blockIdx.x;
  const int cg = bid & 15, rg = bid >> 4;
  const int r0 = rg * ROWS, j0 = cg * COLS;
  const int tid = threadIdx.x;
  const int jp = tid & 15, rr = tid >> 4;     // rr in 0..7
  const int ra = rr, rb = rr + 8;
  const int ca = jp, cb = jp + 16;

  const float* Wm = ws + WS_WM;
  float* hbuf = ws + WS_H;
  float* ystg = ws + WS_YS;
  unsigned* cnt = ((unsigned*)(ws + WS_CNT)) + rg * 32;

  // --- prologue: persist W slices in LDS for the whole kernel ---
  {
    int row = tid >> 2;   // 0..31
    int seg = tid & 3;    // 0..3
    const float4* s1 = (const float4*)(Wm  + (size_t)(j0 + row) * NN);
    const float4* s2 = (const float4*)(W2g + (size_t)(j0 + row) * NN);
#pragma unroll
    for (int i = 0; i < 32; ++i) {
      int g = seg * 32 + i;
      w1f[g * 32 + row] = s1[g];
      w2f[g * 32 + row] = s2[g];
    }
  }
  const float b1a = b1[j0 + ca], b1b = b1[j0 + cb];
  const float b2a = b2[j0 + ca], b2b = b2[j0 + cb];
  __syncthreads();

  unsigned epoch = 0;
  float yb00 = 0.f, yb01 = 0.f, yb10 = 0.f, yb11 = 0.f;  // y_base patch
  float ac00 = 0.f, ac01 = 0.f, ac10 = 0.f, ac11 = 0.f;  // k accumulation

  for (int t = 0; t < NT - 1; ++t) {
    const float dt = tspan[t + 1] - tspan[t];
#pragma unroll 1
    for (int s = 0; s < 4; ++s) {
      // --- stage y (or intermediate state) into LDS ---
      {
        int row = tid >> 3;   // 0..15
        int seg = tid & 7;    // 0..7
        const float* base = (s == 0)
            ? (out  + ((size_t)(r0 + row) * NT + t) * NN)
            : (ystg + (size_t)(r0 + row) * NN);
        const float4* src = (const float4*)base;
#pragma unroll
        for (int i = 0; i < 16; ++i) {
          int g = seg * 16 + i;
          yf[g * 16 + row] = src[g];
        }
      }
      __syncthreads();

      if (s == 0) {  // latch y_base for this step (plane t, own patch)
        yb00 = out[((size_t)(r0 + ra) * NT + t) * NN + j0 + ca];
        yb01 = out[((size_t)(r0 + ra) * NT + t) * NN + j0 + cb];
        yb10 = out[((size_t)(r0 + rb) * NT + t) * NN + j0 + ca];
        yb11 = out[((size_t)(r0 + rb) * NT + t) * NN + j0 + cb];
      }

      // --- GEMM1 + bias + tanh -> h patch to global ---
      {
        float x00, x01, x10, x11;
        gemm_tile(yf, w1f, ra, rb, ca, cb, x00, x01, x10, x11);
        float h00 = tanhf(x00 + b1a);
        float h01 = tanhf(x01 + b1b);
        float h10 = tanhf(x10 + b1a);
        float h11 = tanhf(x11 + b1b);
        hbuf[(size_t)(r0 + ra) * NN + j0 + ca] = h00;
        hbuf[(size_t)(r0 + ra) * NN + j0 + cb] = h01;
        hbuf[(size_t)(r0 + rb) * NN + j0 + ca] = h10;
        hbuf[(size_t)(r0 + rb) * NN + j0 + cb] = h11;
      }
      team_release(cnt); ++epoch;
      team_wait(cnt, NTEAM * epoch);

      // --- stage full h rows into LDS ---
      {
        int row = tid >> 3;
        int seg = tid & 7;
        const float4* src = (const float4*)(hbuf + (size_t)(r0 + row) * NN);
#pragma unroll
        for (int i = 0; i < 16; ++i) {
          int g = seg * 16 + i;
          yf[g * 16 + row] = src[g];
        }
      }
      __syncthreads();

      // --- GEMM2 + bias -> k values ---
      float k00, k01, k10, k11;
      gemm_tile(yf, w2f, ra, rb, ca, cb, k00, k01, k10, k11);
      k00 += b2a; k01 += b2b; k10 += b2a; k11 += b2b;

      // --- RK4 combine for this block's patch ---
      if (s == 0) {
        ac00 = k00; ac01 = k01; ac10 = k10; ac11 = k11;
        ystg[(size_t)(r0 + ra) * NN + j0 + ca] = yb00 + (dt * k00) * 0.5f;
        ystg[(size_t)(r0 + ra) * NN + j0 + cb] = yb01 + (dt * k01) * 0.5f;
        ystg[(size_t)(r0 + rb) * NN + j0 + ca] = yb10 + (dt * k10) * 0.5f;
        ystg[(size_t)(r0 + rb) * NN + j0 + cb] = yb11 + (dt * k11) * 0.5f;
      } else if (s == 1) {
        ac00 += 2.f * k00; ac01 += 2.f * k01; ac10 += 2.f * k10; ac11 += 2.f * k11;
        ystg[(size_t)(r0 + ra) * NN + j0 + ca] = yb00 + (dt * k00) * 0.5f;
        ystg[(size_t)(r0 + ra) * NN + j0 + cb] = yb01 + (dt * k01) * 0.5f;
        ystg[(size_t)(r0 + rb) * NN + j0 + ca] = yb10 + (dt * k10) * 0.5f;
        ystg[(size_t)(r0 + rb) * NN + j0 + cb] = yb11 + (dt * k11) * 0.5f;
      } else if (s == 2) {
        ac00 += 2.f * k00; ac01 += 2.f * k01; ac10 += 2.f * k10; ac11 += 2.f * k11;
        ystg[(size_t)(r0 + ra) * NN + j0 + ca] = yb00 + dt * k00;
        ystg[(size_t)(r0 + ra) * NN + j0 + cb] = yb01 + dt * k01;
        ystg[(size_t)(r0 + rb) * NN + j0 + ca] = yb10 + dt * k10;
        ystg[(size_t)(r0 + rb) * NN + j0 + cb] = yb11 + dt * k11;
      } else {
        ac00 += k00; ac01 += k01; ac10 += k10; ac11 += k11;
        const float c = dt / 6.0f;
        out[((size_t)(r0 + ra) * NT + (t + 1)) * NN + j0 + ca] = yb00 + c * ac00;
        out[((size_t)(r0 + ra) * NT + (t + 1)) * NN + j0 + cb] = yb01 + c * ac01;
        out[((size_t)(r0 + rb) * NT + (t + 1)) * NN + j0 + ca] = yb10 + c * ac10;
        out[((size_t)(r0 + rb) * NT + (t + 1)) * NN + j0 + cb] = yb11 + c * ac11;
      }
      team_release(cnt); ++epoch;
      team_wait(cnt, NTEAM * epoch);
    }
  }
}

extern "C" void kernel_launch(void* const* d_in, const int* in_sizes, int n_in,
                              void* d_out, int out_size, void* d_ws, size_t ws_size,
                              hipStream_t stream) {
  const float* x_init = (const float*)d_in[0];
  const float* tspan  = (const float*)d_in[1];
  const float* W1     = (const float*)d_in[2];
  const float* b1     = (const float*)d_in[3];
  const float* W2     = (const float*)d_in[4];
  const float* b2     = (const float*)d_in[5];
  const float* mask   = (const float*)d_in[6];
  float* out = (float*)d_out;
  float* ws  = (float*)d_ws;

  hipLaunchKernelGGL(k_init, dim3(256), dim3(256), 0, stream,
                     W1, mask, x_init, ws, out);

  const unsigned ldsBytes = 160 * 1024;  // w1(64K) + w2(64K) + y(32K)
  hipFuncSetAttribute((const void*)k_ode,
                      hipFuncAttributeMaxDynamicSharedMemorySize, (int)ldsBytes);

  void* args[] = { (void*)&tspan, (void*)&W2, (void*)&b1, (void*)&b2,
                   (void*)&ws, (void*)&out };
  hipLaunchCooperativeKernel((const void*)k_ode, dim3(256), dim3(TPB),
                             args, ldsBytes, stream);
}

// Round 2
// 45416.656 us; speedup vs baseline: 1.0101x; 1.0101x over previous
//
#include <hip/hip_runtime.h>
#include <math.h>

#define NN 512      // nodes
#define NB 256      // batch
#define NT 200      // time steps
#define GPR 128     // float4 granules per 512-float row
#define TPB 256
#define NTEAM 16    // blocks per team

// ws layout in floats
#define WS_WM  0                       // Wm = W1*mask  [512*512]
#define WS_H   (NN*NN)                 // h buffer      [256*512]
#define WS_YS  (WS_H + NB*NN)          // y_stage       [256*512]
#define WS_CNT (WS_YS + NB*NN)         // 16 team counters, stride 32 u32

#define FMA4(acc, u, v) do { \
  acc.x = fmaf(u.x, v.x, acc.x); acc.y = fmaf(u.y, v.y, acc.y); \
  acc.z = fmaf(u.z, v.z, acc.z); acc.w = fmaf(u.w, v.w, acc.w); } while (0)

__global__ __launch_bounds__(256)
void k_init(const float* __restrict__ W1, const float* __restrict__ mask,
            const float* __restrict__ x_init, float* __restrict__ ws,
            float* __restrict__ out) {
  int gt = blockIdx.x * 256 + threadIdx.x;
  int stride = gridDim.x * 256;
  for (int i = gt; i < NN * NN; i += stride) ws[WS_WM + i] = W1[i] * mask[i];
  for (int i = gt; i < NB * NN; i += stride) {
    int r = i >> 9, n = i & (NN - 1);
    float v = x_init[i];
    out[((size_t)r * NT) * NN + n] = v;   // traj[:,0,:] = x_init
    ws[WS_YS + i] = v;                    // seed y_stage
  }
  if (gt < 16 * 32) ((unsigned*)(ws + WS_CNT))[gt] = 0u;
}

__device__ __forceinline__ void team_release(unsigned* cnt) {
  __syncthreads();                 // drains each wave's vmcnt before barrier
  if (threadIdx.x == 0) {
    __threadfence();               // release: write back L2
    atomicAdd(cnt, 1u);            // device-scope, lands at MALL
  }
}

__device__ __forceinline__ void team_wait(unsigned* cnt, unsigned target) {
  if (threadIdx.x == 0) {
    while (__hip_atomic_load(cnt, __ATOMIC_RELAXED, __HIP_MEMORY_SCOPE_AGENT) < target)
      __builtin_amdgcn_s_sleep(2);
  }
  __syncthreads();
  __threadfence();                 // acquire: invalidate L1/L2
}

// Stage 16 rows x 512 floats (row stride NN in global) into yf, K-interleaved
// linear layout: yf[row*GPR + g]. Write bank-quad = seg%8 -> conflict-free.
__device__ __forceinline__ void stage_rows(float4* __restrict__ yf,
                                           const float* __restrict__ src_base,
                                           int tid) {
  const int row = tid >> 4;        // 0..15
  const int seg = tid & 15;        // 0..15
  const float4* s = (const float4*)(src_base + (size_t)row * NN);
  float4* d = yf + row * GPR;
#pragma unroll
  for (int j = 0; j < 8; ++j) {
    int g = j * 16 + seg;
    d[g] = s[g];
  }
}

// 4x4 tile, K split 8-way over kc lanes (granules g = j*8 + kc, j=0..15),
// then 3-round shfl_xor butterfly so all lanes hold full K=512 sums.
__device__ __forceinline__ void gemm16(const float4* __restrict__ yp,
                                       const float4* __restrict__ wp,
                                       float out[4][4]) {
  float4 acc[4][4];
#pragma unroll
  for (int r = 0; r < 4; ++r)
#pragma unroll
    for (int c = 0; c < 4; ++c) acc[r][c] = make_float4(0.f, 0.f, 0.f, 0.f);

#pragma unroll 4
  for (int j = 0; j < 16; ++j) {
    float4 yv[4], wv[4];
#pragma unroll
    for (int r = 0; r < 4; ++r) yv[r] = yp[r * GPR + j * 8];
#pragma unroll
    for (int c = 0; c < 4; ++c) wv[c] = wp[c * GPR + j * 8];
#pragma unroll
    for (int r = 0; r < 4; ++r)
#pragma unroll
      for (int c = 0; c < 4; ++c) FMA4(acc[r][c], yv[r], wv[c]);
  }
#pragma unroll
  for (int r = 0; r < 4; ++r)
#pragma unroll
    for (int c = 0; c < 4; ++c) {
      float4 a = acc[r][c];
      float s = (a.x + a.y) + (a.z + a.w);
      s += __shfl_xor(s, 1);
      s += __shfl_xor(s, 2);
      s += __shfl_xor(s, 4);
      out[r][c] = s;
    }
}

__global__ __launch_bounds__(TPB, 1)
void k_ode(const float* __restrict__ tspan,
           const float* __restrict__ W2g,
           const float* __restrict__ b1,
           const float* __restrict__ b2,
           float* __restrict__ ws,
           float* __restrict__ out) {
  extern __shared__ float lds[];
  float4* w1f = (float4*)lds;          // [32 cols][128 granules]
  float4* w2f = w1f + 32 * GPR;        // [32][128]
  float4* yf  = w2f + 32 * GPR;        // [16 rows][128]

  const int bid = blockIdx.x;
  const int cg = bid & 15, rg = bid >> 4;
  const int r0 = rg * 16, j0 = cg * 32;
  const int tid = threadIdx.x;
  const int kc = tid & 7;              // K-chunk (lane bits 0-2)
  const int ct = (tid >> 3) & 7;       // col-tile: cols ct*4..+3
  const int rt = tid >> 6;             // row-tile (= wave): rows rt*4..+3

  const float* Wm = ws + WS_WM;
  float* hbuf = ws + WS_H;
  float* ystg = ws + WS_YS;
  unsigned* cnt = ((unsigned*)(ws + WS_CNT)) + rg * 32;

  // --- prologue: persist weight slices in LDS (K-interleaved layout) ---
  {
    const int col = tid >> 3;          // 0..31
    const int seg = tid & 7;           // 0..7
    const float4* s1 = (const float4*)(Wm  + (size_t)(j0 + col) * NN);
    const float4* s2 = (const float4*)(W2g + (size_t)(j0 + col) * NN);
    float4* d1 = w1f + col * GPR;
    float4* d2 = w2f + col * GPR;
#pragma unroll
    for (int j = 0; j < 16; ++j) {
      int g = j * 8 + seg;
      d1[g] = s1[g];
      d2[g] = s2[g];
    }
  }
  float b1v[4], b2v[4];
#pragma unroll
  for (int c = 0; c < 4; ++c) {
    b1v[c] = b1[j0 + ct * 4 + c];
    b2v[c] = b2[j0 + ct * 4 + c];
  }
  __syncthreads();

  const float4* yp  = yf  + rt * 4 * GPR + kc;
  const float4* wp1 = w1f + ct * 4 * GPR + kc;
  const float4* wp2 = w2f + ct * 4 * GPR + kc;

  unsigned epoch = 0;
  float yb[4][4];                      // y_base patch (used by kc==0 lanes)
  float ac[4][4];                      // RK4 k-accumulation

  for (int t = 0; t < NT - 1; ++t) {
    const float dt = tspan[t + 1] - tspan[t];
#pragma unroll 1
    for (int s = 0; s < 4; ++s) {
      // --- stage y_s into LDS (ystg holds current stage state) ---
      stage_rows(yf, ystg + (size_t)r0 * NN, tid);
      __syncthreads();

      if (s == 0) {  // latch y_base for this RK4 step from LDS
#pragma unroll
        for (int r = 0; r < 4; ++r) {
          float4 q = yf[(rt * 4 + r) * GPR + cg * 8 + ct];
          yb[r][0] = q.x; yb[r][1] = q.y; yb[r][2] = q.z; yb[r][3] = q.w;
        }
      }

      // --- GEMM1 + bias + tanh -> h patch ---
      {
        float x[4][4];
        gemm16(yp, wp1, x);
        float h[4][4];
#pragma unroll
        for (int r = 0; r < 4; ++r)
#pragma unroll
          for (int c = 0; c < 4; ++c) h[r][c] = tanhf(x[r][c] + b1v[c]);
        if (kc == 0) {
#pragma unroll
          for (int r = 0; r < 4; ++r) {
            float4 v = make_float4(h[r][0], h[r][1], h[r][2], h[r][3]);
            *(float4*)(hbuf + (size_t)(r0 + rt * 4 + r) * NN + j0 + ct * 4) = v;
          }
        }
      }
      team_release(cnt); ++epoch;
      team_wait(cnt, NTEAM * epoch);

      // --- stage full h rows, GEMM2 + bias -> k ---
      stage_rows(yf, hbuf + (size_t)r0 * NN, tid);
      __syncthreads();

      float k[4][4];
      gemm16(yp, wp2, k);
#pragma unroll
      for (int r = 0; r < 4; ++r)
#pragma unroll
        for (int c = 0; c < 4; ++c) k[r][c] += b2v[c];

      // --- RK4 combine (kc==0 lanes own the patch writes) ---
      if (kc == 0) {
#pragma unroll
        for (int r = 0; r < 4; ++r) {
          float yn[4];
          if (s == 0) {
#pragma unroll
            for (int c = 0; c < 4; ++c) {
              ac[r][c] = k[r][c];
              yn[c] = yb[r][c] + (dt * k[r][c]) * 0.5f;
            }
          } else if (s == 1) {
#pragma unroll
            for (int c = 0; c < 4; ++c) {
              ac[r][c] += 2.f * k[r][c];
              yn[c] = yb[r][c] + (dt * k[r][c]) * 0.5f;
            }
          } else if (s == 2) {
#pragma unroll
            for (int c = 0; c < 4; ++c) {
              ac[r][c] += 2.f * k[r][c];
              yn[c] = yb[r][c] + dt * k[r][c];
            }
          } else {
            const float c6 = dt / 6.0f;
#pragma unroll
            for (int c = 0; c < 4; ++c) {
              ac[r][c] += k[r][c];
              yn[c] = yb[r][c] + c6 * ac[r][c];
            }
            *(float4*)(out + ((size_t)(r0 + rt * 4 + r) * NT + (t + 1)) * NN
                       + j0 + ct * 4) = make_float4(yn[0], yn[1], yn[2], yn[3]);
          }
          *(float4*)(ystg + (size_t)(r0 + rt * 4 + r) * NN + j0 + ct * 4) =
              make_float4(yn[0], yn[1], yn[2], yn[3]);
        }
      }
      team_release(cnt); ++epoch;
      team_wait(cnt, NTEAM * epoch);
    }
  }
}

extern "C" void kernel_launch(void* const* d_in, const int* in_sizes, int n_in,
                              void* d_out, int out_size, void* d_ws, size_t ws_size,
                              hipStream_t stream) {
  const float* x_init = (const float*)d_in[0];
  const float* tspan  = (const float*)d_in[1];
  const float* W1     = (const float*)d_in[2];
  const float* b1     = (const float*)d_in[3];
  const float* W2     = (const float*)d_in[4];
  const float* b2     = (const float*)d_in[5];
  const float* mask   = (const float*)d_in[6];
  float* out = (float*)d_out;
  float* ws  = (float*)d_ws;

  hipLaunchKernelGGL(k_init, dim3(256), dim3(256), 0, stream,
                     W1, mask, x_init, ws, out);

  const unsigned ldsBytes = 160 * 1024;  // w1(64K) + w2(64K) + y(32K)
  hipFuncSetAttribute((const void*)k_ode,
                      hipFuncAttributeMaxDynamicSharedMemorySize, (int)ldsBytes);

  void* args[] = { (void*)&tspan, (void*)&W2, (void*)&b1, (void*)&b2,
                   (void*)&ws, (void*)&out };
  hipLaunchCooperativeKernel((const void*)k_ode, dim3(256), dim3(TPB),
                             args, ldsBytes, stream);
}

// Round 6
// 14846.042 us; speedup vs baseline: 3.0902x; 3.0592x over previous
//
#include <hip/hip_runtime.h>
#include <math.h>

#define NN 512      // nodes
#define NB 256      // batch
#define NT 200      // time steps
#define GPR 128     // float4 granules per 512-float row
#define TPB 256
#define NTEAM 16    // blocks per team

typedef unsigned long long u64;

// ws layout in floats
#define WS_WM  0                       // Wm = W1*mask  [512*512]
#define WS_H   (NN*NN)                 // h buffer      [256*512]
#define WS_YS  (WS_H + NB*NN)          // y_stage       [256*512]
#define WS_CNT (WS_YS + NB*NN)         // 16 team counters, stride 32 u32

#define FMA4(acc, u, v) do { \
  acc.x = fmaf(u.x, v.x, acc.x); acc.y = fmaf(u.y, v.y, acc.y); \
  acc.z = fmaf(u.z, v.z, acc.z); acc.w = fmaf(u.w, v.w, acc.w); } while (0)

// ---- MALL-coherent ops via compiler-generated scoped atomics (no asm) ----
__device__ __forceinline__ void sysst_u64(u64* p, u64 v) {
  __hip_atomic_store(p, v, __ATOMIC_RELAXED, __HIP_MEMORY_SCOPE_SYSTEM);
}
__device__ __forceinline__ u64 sysld_u64(const u64* p) {
  return __hip_atomic_load(p, __ATOMIC_RELAXED, __HIP_MEMORY_SCOPE_SYSTEM);
}
__device__ __forceinline__ void sysst_f2(float* p, float a, float b) {
  union { u64 q; float f[2]; } u; u.f[0] = a; u.f[1] = b;
  sysst_u64((u64*)p, u.q);
}

__global__ __launch_bounds__(256)
void k_init(const float* __restrict__ W1, const float* __restrict__ mask,
            const float* __restrict__ x_init, float* __restrict__ ws,
            float* __restrict__ out) {
  int gt = blockIdx.x * 256 + threadIdx.x;
  int stride = gridDim.x * 256;
  for (int i = gt; i < NN * NN; i += stride) ws[WS_WM + i] = W1[i] * mask[i];
  // seed y_stage (MALL-coherent) and traj t=0 plane (plain), 2 floats/iter
  for (int i = gt; i < NB * NN / 2; i += stride) {
    u64 q = ((const u64*)x_init)[i];
    int r = i >> 8, np = i & 255;           // row, float-pair index
    *((u64*)(out + (size_t)r * NT * NN) + np) = q;   // traj[:,0,:]
    sysst_u64((u64*)(ws + WS_YS) + i, q);            // y_stage at MALL
  }
  if (gt < 16 * 32)
    __hip_atomic_store(((unsigned*)(ws + WS_CNT)) + gt, 0u,
                       __ATOMIC_RELAXED, __HIP_MEMORY_SCOPE_SYSTEM);
}

// release: __syncthreads drains vmcnt(0) (all sys-stores at MALL), then add
__device__ __forceinline__ void team_release(unsigned* cnt) {
  __syncthreads();
  if (threadIdx.x == 0) atomicAdd(cnt, 1u);   // device scope, lands at MALL
}

// acquire: poll fresh MALL value (agent-relaxed bypasses L2); no inv needed
__device__ __forceinline__ void team_wait(unsigned* cnt, unsigned target) {
  if (threadIdx.x == 0) {
    while (__hip_atomic_load(cnt, __ATOMIC_RELAXED,
                             __HIP_MEMORY_SCOPE_AGENT) < target)
      __builtin_amdgcn_s_sleep(2);
  }
  __syncthreads();
}

// Stage 16 rows x 512 floats into LDS linear [16][512] via u64 sys-loads.
__device__ __forceinline__ void stage_rows_sys(float* __restrict__ ldsbase,
                                               const float* __restrict__ src,
                                               int tid) {
  const int row = tid >> 4;        // 0..15
  const int seg = tid & 15;        // 0..15
  const u64* s = (const u64*)(src + (size_t)row * NN) + seg;
  u64* d = (u64*)(ldsbase + row * NN) + seg;
#pragma unroll
  for (int u = 0; u < 16; ++u) d[u * 16] = sysld_u64(s + u * 16);
}

// 4x4 tile, K split 8-way over kc lanes (granules g = j*8 + kc, j=0..15),
// then 3-round shfl_xor butterfly so all lanes hold full K=512 sums.
__device__ __forceinline__ void gemm16(const float4* __restrict__ yp,
                                       const float4* __restrict__ wp,
                                       float out[4][4]) {
  float4 acc[4][4];
#pragma unroll
  for (int r = 0; r < 4; ++r)
#pragma unroll
    for (int c = 0; c < 4; ++c) acc[r][c] = make_float4(0.f, 0.f, 0.f, 0.f);

#pragma unroll 4
  for (int j = 0; j < 16; ++j) {
    float4 yv[4], wv[4];
#pragma unroll
    for (int r = 0; r < 4; ++r) yv[r] = yp[r * GPR + j * 8];
#pragma unroll
    for (int c = 0; c < 4; ++c) wv[c] = wp[c * GPR + j * 8];
#pragma unroll
    for (int r = 0; r < 4; ++r)
#pragma unroll
      for (int c = 0; c < 4; ++c) FMA4(acc[r][c], yv[r], wv[c]);
  }
#pragma unroll
  for (int r = 0; r < 4; ++r)
#pragma unroll
    for (int c = 0; c < 4; ++c) {
      float4 a = acc[r][c];
      float s = (a.x + a.y) + (a.z + a.w);
      s += __shfl_xor(s, 1);
      s += __shfl_xor(s, 2);
      s += __shfl_xor(s, 4);
      out[r][c] = s;
    }
}

__global__ __launch_bounds__(TPB, 1)
void k_ode(const float* __restrict__ tspan,
           const float* __restrict__ W2g,
           const float* __restrict__ b1,
           const float* __restrict__ b2,
           float* __restrict__ ws,
           float* __restrict__ out) {
  extern __shared__ float lds[];
  float4* w1f = (float4*)lds;          // [32 cols][128 granules]
  float4* w2f = w1f + 32 * GPR;        // [32][128]
  float4* yf  = w2f + 32 * GPR;        // [16 rows][128]

  const int bid = blockIdx.x;
  const int cg = bid & 15, rg = bid >> 4;
  const int r0 = rg * 16, j0 = cg * 32;
  const int tid = threadIdx.x;
  const int kc = tid & 7;              // K-chunk (lane bits 0-2)
  const int ct = (tid >> 3) & 7;       // col-tile: cols ct*4..+3
  const int rt = tid >> 6;             // row-tile (= wave): rows rt*4..+3

  const float* Wm = ws + WS_WM;
  float* hbuf = ws + WS_H;
  float* ystg = ws + WS_YS;
  unsigned* cnt = ((unsigned*)(ws + WS_CNT)) + rg * 32;

  // --- prologue: persist weight slices in LDS (plain cached loads) ---
  {
    const int col = tid >> 3;          // 0..31
    const int seg = tid & 7;           // 0..7
    const float4* s1 = (const float4*)(Wm  + (size_t)(j0 + col) * NN);
    const float4* s2 = (const float4*)(W2g + (size_t)(j0 + col) * NN);
    float4* d1 = w1f + col * GPR;
    float4* d2 = w2f + col * GPR;
#pragma unroll
    for (int j = 0; j < 16; ++j) {
      int g = j * 8 + seg;
      d1[g] = s1[g];
      d2[g] = s2[g];
    }
  }
  float b1v[4], b2v[4];
#pragma unroll
  for (int c = 0; c < 4; ++c) {
    b1v[c] = b1[j0 + ct * 4 + c];
    b2v[c] = b2[j0 + ct * 4 + c];
  }
  __syncthreads();

  const float4* yp  = yf  + rt * 4 * GPR + kc;
  const float4* wp1 = w1f + ct * 4 * GPR + kc;
  const float4* wp2 = w2f + ct * 4 * GPR + kc;

  unsigned epoch = 0;
  float yb[4][4];                      // y_base patch (kc==0 lanes)
  float ac[4][4];                      // RK4 k-accumulation

  for (int t = 0; t < NT - 1; ++t) {
    const float dt = tspan[t + 1] - tspan[t];
#pragma unroll 1
    for (int s = 0; s < 4; ++s) {
      // --- stage y_s into LDS (ystg holds current stage state, at MALL) ---
      stage_rows_sys((float*)yf, ystg + (size_t)r0 * NN, tid);
      __syncthreads();

      if (s == 0) {  // latch y_base for this RK4 step from LDS
#pragma unroll
        for (int r = 0; r < 4; ++r) {
          float4 q = yf[(rt * 4 + r) * GPR + cg * 8 + ct];
          yb[r][0] = q.x; yb[r][1] = q.y; yb[r][2] = q.z; yb[r][3] = q.w;
        }
      }

      // --- GEMM1 + bias + tanh -> h patch (sys store to MALL) ---
      {
        float x[4][4];
        gemm16(yp, wp1, x);
        if (kc == 0) {
#pragma unroll
          for (int r = 0; r < 4; ++r) {
            float* hp = hbuf + (size_t)(r0 + rt * 4 + r) * NN + j0 + ct * 4;
            sysst_f2(hp,     tanhf(x[r][0] + b1v[0]), tanhf(x[r][1] + b1v[1]));
            sysst_f2(hp + 2, tanhf(x[r][2] + b1v[2]), tanhf(x[r][3] + b1v[3]));
          }
        }
      }
      team_release(cnt); ++epoch;
      team_wait(cnt, NTEAM * epoch);

      // --- stage full h rows, GEMM2 + bias -> k ---
      stage_rows_sys((float*)yf, hbuf + (size_t)r0 * NN, tid);
      __syncthreads();

      float k[4][4];
      gemm16(yp, wp2, k);
#pragma unroll
      for (int r = 0; r < 4; ++r)
#pragma unroll
        for (int c = 0; c < 4; ++c) k[r][c] += b2v[c];

      // --- RK4 combine (kc==0 lanes own the patch writes) ---
      if (kc == 0) {
#pragma unroll
        for (int r = 0; r < 4; ++r) {
          float yn[4];
          if (s == 0) {
#pragma unroll
            for (int c = 0; c < 4; ++c) {
              ac[r][c] = k[r][c];
              yn[c] = yb[r][c] + (dt * k[r][c]) * 0.5f;
            }
          } else if (s == 1) {
#pragma unroll
            for (int c = 0; c < 4; ++c) {
              ac[r][c] += 2.f * k[r][c];
              yn[c] = yb[r][c] + (dt * k[r][c]) * 0.5f;
            }
          } else if (s == 2) {
#pragma unroll
            for (int c = 0; c < 4; ++c) {
              ac[r][c] += 2.f * k[r][c];
              yn[c] = yb[r][c] + dt * k[r][c];
            }
          } else {
            const float c6 = dt / 6.0f;
#pragma unroll
            for (int c = 0; c < 4; ++c) {
              ac[r][c] += k[r][c];
              yn[c] = yb[r][c] + c6 * ac[r][c];
            }
            *(float4*)(out + ((size_t)(r0 + rt * 4 + r) * NT + (t + 1)) * NN
                       + j0 + ct * 4) = make_float4(yn[0], yn[1], yn[2], yn[3]);
          }
          float* sp = ystg + (size_t)(r0 + rt * 4 + r) * NN + j0 + ct * 4;
          sysst_f2(sp,     yn[0], yn[1]);
          sysst_f2(sp + 2, yn[2], yn[3]);
        }
      }
      team_release(cnt); ++epoch;
      team_wait(cnt, NTEAM * epoch);
    }
  }
}

extern "C" void kernel_launch(void* const* d_in, const int* in_sizes, int n_in,
                              void* d_out, int out_size, void* d_ws, size_t ws_size,
                              hipStream_t stream) {
  const float* x_init = (const float*)d_in[0];
  const float* tspan  = (const float*)d_in[1];
  const float* W1     = (const float*)d_in[2];
  const float* b1     = (const float*)d_in[3];
  const float* W2     = (const float*)d_in[4];
  const float* b2     = (const float*)d_in[5];
  const float* mask   = (const float*)d_in[6];
  float* out = (float*)d_out;
  float* ws  = (float*)d_ws;

  hipLaunchKernelGGL(k_init, dim3(256), dim3(256), 0, stream,
                     W1, mask, x_init, ws, out);

  const unsigned ldsBytes = 160 * 1024;  // w1(64K) + w2(64K) + y(32K)
  (void)hipFuncSetAttribute((const void*)k_ode,
                            hipFuncAttributeMaxDynamicSharedMemorySize,
                            (int)ldsBytes);

  // Plain launch: 160KB LDS forces 1 block/CU; grid 256 == CU count, so all
  // blocks are co-resident by capacity — spin barrier is safe without
  // cooperative launch.
  hipLaunchKernelGGL(k_ode, dim3(256), dim3(TPB), ldsBytes, stream,
                     tspan, W2, b1, b2, ws, out);
}

// Round 7
// 9033.072 us; speedup vs baseline: 5.0788x; 1.6435x over previous
//
#include <hip/hip_runtime.h>
#include <math.h>

#define NN 512      // nodes
#define NB 256      // batch
#define NT 200      // time steps
#define TPB 256
#define NTEAM 16    // blocks per team

typedef unsigned long long u64;
typedef _Float16 half8 __attribute__((ext_vector_type(8)));
typedef float f32x4 __attribute__((ext_vector_type(4)));

// ws layout in floats
#define WS_WM  0                       // Wm = W1*mask  [512*512]
#define WS_H   (NN*NN)                 // h buffer      [256*512]
#define WS_YS  (WS_H + NB*NN)          // y_stage       [256*512]
#define WS_CNT (WS_YS + NB*NN)         // 16 team counters, stride 32 u32

// LDS offsets in halfs (total 81920 halfs = 160 KiB)
#define L_W1H 0
#define L_W1L 16384
#define L_W2H 32768
#define L_W2L 49152
#define L_YH  65536
#define L_YL  73728

// ---- MALL-coherent ops via compiler-generated scoped atomics (no asm) ----
__device__ __forceinline__ void sysst_u64(u64* p, u64 v) {
  __hip_atomic_store(p, v, __ATOMIC_RELAXED, __HIP_MEMORY_SCOPE_SYSTEM);
}
__device__ __forceinline__ u64 sysld_u64(const u64* p) {
  return __hip_atomic_load(p, __ATOMIC_RELAXED, __HIP_MEMORY_SCOPE_SYSTEM);
}
__device__ __forceinline__ void sysst_f2(float* p, float a, float b) {
  union { u64 q; float f[2]; } u; u.f[0] = a; u.f[1] = b;
  sysst_u64((u64*)p, u.q);
}

__global__ __launch_bounds__(256)
void k_init(const float* __restrict__ W1, const float* __restrict__ mask,
            const float* __restrict__ x_init, float* __restrict__ ws,
            float* __restrict__ out) {
  int gt = blockIdx.x * 256 + threadIdx.x;
  int stride = gridDim.x * 256;
  for (int i = gt; i < NN * NN; i += stride) ws[WS_WM + i] = W1[i] * mask[i];
  for (int i = gt; i < NB * NN / 2; i += stride) {
    u64 q = ((const u64*)x_init)[i];
    int r = i >> 8, np = i & 255;
    *((u64*)(out + (size_t)r * NT * NN) + np) = q;   // traj[:,0,:]
    sysst_u64((u64*)(ws + WS_YS) + i, q);            // y_stage at MALL
  }
  if (gt < 16 * 32)
    __hip_atomic_store(((unsigned*)(ws + WS_CNT)) + gt, 0u,
                       __ATOMIC_RELAXED, __HIP_MEMORY_SCOPE_SYSTEM);
}

__device__ __forceinline__ void team_release(unsigned* cnt) {
  __syncthreads();
  if (threadIdx.x == 0) atomicAdd(cnt, 1u);
}
__device__ __forceinline__ void team_wait(unsigned* cnt, unsigned target) {
  if (threadIdx.x == 0) {
    while (__hip_atomic_load(cnt, __ATOMIC_RELAXED,
                             __HIP_MEMORY_SCOPE_AGENT) < target)
      __builtin_amdgcn_s_sleep(2);
  }
  __syncthreads();
}

// split 8 fp32 (two f32x4) into hi fp16 + lo fp16 (lo scaled x2048)
__device__ __forceinline__ void split8(const float* p, half8& hv, half8& lv) {
  const f32x4* p4 = (const f32x4*)p;
  f32x4 v0 = p4[0], v1 = p4[1];
#pragma unroll
  for (int e = 0; e < 4; ++e) {
    float f = v0[e]; _Float16 h = (_Float16)f;
    hv[e] = h; lv[e] = (_Float16)((f - (float)h) * 2048.0f);
  }
#pragma unroll
  for (int e = 0; e < 4; ++e) {
    float f = v1[e]; _Float16 h = (_Float16)f;
    hv[4 + e] = h; lv[4 + e] = (_Float16)((f - (float)h) * 2048.0f);
  }
}

// Stage 16 rows x 512 fp32 from MALL -> split fp16 planes in LDS (swizzled).
__device__ __forceinline__ void stage_split(_Float16* __restrict__ pH,
                                            _Float16* __restrict__ pL,
                                            const float* __restrict__ src,
                                            int tid) {
  const int row = tid >> 4;        // 0..15
  const int seg = tid & 15;        // 0..15  -> k base seg*32
  const u64* s = (const u64*)(src + (size_t)row * NN + seg * 32);
  u64 tmp[16];
#pragma unroll
  for (int i = 0; i < 16; ++i) tmp[i] = sysld_u64(s + i);
  const int swz = row & 7;
  half8* dH = (half8*)pH;
  half8* dL = (half8*)pL;
#pragma unroll
  for (int q = 0; q < 4; ++q) {
    half8 hv, lv;
#pragma unroll
    for (int e = 0; e < 4; ++e) {
      union { u64 q64; float f[2]; } u; u.q64 = tmp[q * 4 + e];
#pragma unroll
      for (int x = 0; x < 2; ++x) {
        float f = u.f[x]; _Float16 h = (_Float16)f;
        hv[e * 2 + x] = h;
        lv[e * 2 + x] = (_Float16)((f - (float)h) * 2048.0f);
      }
    }
    int g = seg * 4 + q;
    int idx = row * 64 + (g ^ swz);
    dH[idx] = hv; dL[idx] = lv;
  }
}

// Wave-level K-partial GEMM: this wave covers K range [wv*128, wv*128+128).
// acc[n] = sum_k y[row][k] * w[col + n*16][k]  (split-fp16, 3 mfma per tile)
__device__ __forceinline__ void gemm_mfma(const _Float16* aHb, const _Float16* aLb,
                                          const _Float16* bHb, const _Float16* bLb,
                                          int lane, int wv, f32x4 acc[2]) {
  const int rc = lane & 15;
  const int kg = lane >> 4;
  const int swz = rc & 7;
  const half8* pAH = (const half8*)aHb;
  const half8* pAL = (const half8*)aLb;
  const half8* pBH = (const half8*)bHb;
  const half8* pBL = (const half8*)bLb;
  f32x4 hh0 = {0.f, 0.f, 0.f, 0.f}, hh1 = {0.f, 0.f, 0.f, 0.f};
  f32x4 xx0 = {0.f, 0.f, 0.f, 0.f}, xx1 = {0.f, 0.f, 0.f, 0.f};
  const int gbase = wv * 16 + kg;
#pragma unroll
  for (int kt = 0; kt < 4; ++kt) {
    const int gs = (gbase + kt * 4) ^ swz;
    half8 ah = pAH[rc * 64 + gs];
    half8 al = pAL[rc * 64 + gs];
    half8 bh0 = pBH[rc * 64 + gs];
    half8 bl0 = pBL[rc * 64 + gs];
    half8 bh1 = pBH[(rc + 16) * 64 + gs];
    half8 bl1 = pBL[(rc + 16) * 64 + gs];
    hh0 = __builtin_amdgcn_mfma_f32_16x16x32_f16(ah, bh0, hh0, 0, 0, 0);
    xx0 = __builtin_amdgcn_mfma_f32_16x16x32_f16(ah, bl0, xx0, 0, 0, 0);
    xx0 = __builtin_amdgcn_mfma_f32_16x16x32_f16(al, bh0, xx0, 0, 0, 0);
    hh1 = __builtin_amdgcn_mfma_f32_16x16x32_f16(ah, bh1, hh1, 0, 0, 0);
    xx1 = __builtin_amdgcn_mfma_f32_16x16x32_f16(ah, bl1, xx1, 0, 0, 0);
    xx1 = __builtin_amdgcn_mfma_f32_16x16x32_f16(al, bh1, xx1, 0, 0, 0);
  }
  acc[0] = hh0 + xx0 * (1.0f / 2048.0f);
  acc[1] = hh1 + xx1 * (1.0f / 2048.0f);
}

__global__ __launch_bounds__(TPB, 1)
void k_ode(const float* __restrict__ tspan,
           const float* __restrict__ W2g,
           const float* __restrict__ b1,
           const float* __restrict__ b2,
           float* __restrict__ ws,
           float* __restrict__ out) {
  extern __shared__ _Float16 ldsh[];
  _Float16* w1H = ldsh + L_W1H;
  _Float16* w1L = ldsh + L_W1L;
  _Float16* w2H = ldsh + L_W2H;
  _Float16* w2L = ldsh + L_W2L;
  _Float16* yH  = ldsh + L_YH;
  _Float16* yL  = ldsh + L_YL;
  float* scratch = (float*)(ldsh + L_YH);   // overlay, used between barriers

  const int bid = blockIdx.x;
  const int cg = bid & 15, rg = bid >> 4;
  const int r0 = rg * 16, j0 = cg * 32;
  const int tid = threadIdx.x;
  const int lane = tid & 63, wv = tid >> 6;
  const int rc = lane & 15, kg = lane >> 4;
  const int orow = tid >> 4, ocol = (tid & 15) * 2;   // output ownership

  const float* Wm = ws + WS_WM;
  float* hbuf = ws + WS_H;
  float* ystg = ws + WS_YS;
  unsigned* cnt = ((unsigned*)(ws + WS_CNT)) + rg * 32;

  // --- prologue: split weight slices into fp16 hi/lo LDS planes ---
  {
    const int col = tid >> 3;          // 0..31
    const int seg = tid & 7;           // 0..7
    const int swz = col & 7;
    const float* s1 = Wm  + (size_t)(j0 + col) * NN + seg * 64;
    const float* s2 = W2g + (size_t)(j0 + col) * NN + seg * 64;
    half8* d1h = (half8*)w1H; half8* d1l = (half8*)w1L;
    half8* d2h = (half8*)w2H; half8* d2l = (half8*)w2L;
#pragma unroll
    for (int q = 0; q < 8; ++q) {
      int g = seg * 8 + q;
      int idx = col * 64 + (g ^ swz);
      half8 hv, lv;
      split8(s1 + q * 8, hv, lv); d1h[idx] = hv; d1l[idx] = lv;
      split8(s2 + q * 8, hv, lv); d2h[idx] = hv; d2l[idx] = lv;
    }
  }
  const float b1v0 = b1[j0 + ocol], b1v1 = b1[j0 + ocol + 1];
  const float b2v0 = b2[j0 + ocol], b2v1 = b2[j0 + ocol + 1];
  __syncthreads();

  unsigned epoch = 0;
  float yb0 = 0.f, yb1 = 0.f, ac0 = 0.f, ac1 = 0.f;

  for (int t = 0; t < NT - 1; ++t) {
    const float dt = tspan[t + 1] - tspan[t];
#pragma unroll 1
    for (int s = 0; s < 4; ++s) {
      // ---------- phase 1: h = tanh(y . W1^T + b1) ----------
      stage_split(yH, yL, ystg + (size_t)r0 * NN, tid);
      if (s == 0) {  // latch fp32 y_base for this RK4 step (own patch)
        union { u64 q; float f[2]; } u;
        u.q = sysld_u64((const u64*)(ystg + (size_t)(r0 + orow) * NN + j0 + ocol));
        yb0 = u.f[0]; yb1 = u.f[1];
      }
      __syncthreads();

      f32x4 acc[2];
      gemm_mfma(yH, yL, w1H, w1L, lane, wv, acc);
      __syncthreads();                    // all plane reads done
#pragma unroll
      for (int n = 0; n < 2; ++n)
#pragma unroll
        for (int r = 0; r < 4; ++r)
          scratch[wv * 512 + (kg * 4 + r) * 32 + rc + n * 16] = acc[n][r];
      __syncthreads();
      {
        float s0 = 0.f, s1 = 0.f;
#pragma unroll
        for (int w = 0; w < 4; ++w) {
          s0 += scratch[w * 512 + orow * 32 + ocol];
          s1 += scratch[w * 512 + orow * 32 + ocol + 1];
        }
        sysst_f2(hbuf + (size_t)(r0 + orow) * NN + j0 + ocol,
                 tanhf(s0 + b1v0), tanhf(s1 + b1v1));
      }
      team_release(cnt); ++epoch;
      team_wait(cnt, NTEAM * epoch);

      // ---------- phase 2: k = h . W2^T + b2, RK4 combine ----------
      stage_split(yH, yL, hbuf + (size_t)r0 * NN, tid);
      __syncthreads();

      gemm_mfma(yH, yL, w2H, w2L, lane, wv, acc);
      __syncthreads();
#pragma unroll
      for (int n = 0; n < 2; ++n)
#pragma unroll
        for (int r = 0; r < 4; ++r)
          scratch[wv * 512 + (kg * 4 + r) * 32 + rc + n * 16] = acc[n][r];
      __syncthreads();
      {
        float k0 = b2v0, k1 = b2v1;
#pragma unroll
        for (int w = 0; w < 4; ++w) {
          k0 += scratch[w * 512 + orow * 32 + ocol];
          k1 += scratch[w * 512 + orow * 32 + ocol + 1];
        }
        float yn0, yn1;
        if (s == 0) {
          ac0 = k0; ac1 = k1;
          yn0 = yb0 + (dt * k0) * 0.5f; yn1 = yb1 + (dt * k1) * 0.5f;
        } else if (s == 1) {
          ac0 += 2.f * k0; ac1 += 2.f * k1;
          yn0 = yb0 + (dt * k0) * 0.5f; yn1 = yb1 + (dt * k1) * 0.5f;
        } else if (s == 2) {
          ac0 += 2.f * k0; ac1 += 2.f * k1;
          yn0 = yb0 + dt * k0; yn1 = yb1 + dt * k1;
        } else {
          ac0 += k0; ac1 += k1;
          const float c6 = dt / 6.0f;
          yn0 = yb0 + c6 * ac0; yn1 = yb1 + c6 * ac1;
          float* op = out + ((size_t)(r0 + orow) * NT + (t + 1)) * NN + j0 + ocol;
          op[0] = yn0; op[1] = yn1;
        }
        sysst_f2(ystg + (size_t)(r0 + orow) * NN + j0 + ocol, yn0, yn1);
      }
      team_release(cnt); ++epoch;
      team_wait(cnt, NTEAM * epoch);
    }
  }
}

extern "C" void kernel_launch(void* const* d_in, const int* in_sizes, int n_in,
                              void* d_out, int out_size, void* d_ws, size_t ws_size,
                              hipStream_t stream) {
  const float* x_init = (const float*)d_in[0];
  const float* tspan  = (const float*)d_in[1];
  const float* W1     = (const float*)d_in[2];
  const float* b1     = (const float*)d_in[3];
  const float* W2     = (const float*)d_in[4];
  const float* b2     = (const float*)d_in[5];
  const float* mask   = (const float*)d_in[6];
  float* out = (float*)d_out;
  float* ws  = (float*)d_ws;

  hipLaunchKernelGGL(k_init, dim3(256), dim3(256), 0, stream,
                     W1, mask, x_init, ws, out);

  const unsigned ldsBytes = 160 * 1024;  // 4 weight planes 128K + y planes 32K
  (void)hipFuncSetAttribute((const void*)k_ode,
                            hipFuncAttributeMaxDynamicSharedMemorySize,
                            (int)ldsBytes);

  // Plain launch: 160KB LDS forces 1 block/CU; grid 256 == CU count, so all
  // blocks are co-resident by capacity — spin barrier is safe.
  hipLaunchKernelGGL(k_ode, dim3(256), dim3(TPB), ldsBytes, stream,
                     tspan, W2, b1, b2, ws, out);
}

// Round 8
// 5158.532 us; speedup vs baseline: 8.8934x; 1.7511x over previous
//
#include <hip/hip_runtime.h>
#include <math.h>

#define NN 512      // nodes
#define NB 256      // batch
#define NT 200      // time steps
#define TPB 256
#define NTEAM 8     // blocks per team (64 cols each)

typedef unsigned long long u64;
typedef _Float16 half8 __attribute__((ext_vector_type(8)));
typedef float f32x4 __attribute__((ext_vector_type(4)));

// ws layout in floats
#define WS_WM  0                       // Wm = W1*mask  [512*512]
#define WS_H   (NN*NN)                 // h buffer      [256*512]
#define WS_YS  (WS_H + NB*NN)          // y_stage       [256*512]
#define WS_CNT (WS_YS + NB*NN)         // 32 team counters, stride 32 u32

// ---- MALL-coherent ops via compiler-generated scoped atomics (no asm) ----
__device__ __forceinline__ void sysst_u64(u64* p, u64 v) {
  __hip_atomic_store(p, v, __ATOMIC_RELAXED, __HIP_MEMORY_SCOPE_SYSTEM);
}
__device__ __forceinline__ u64 sysld_u64(const u64* p) {
  return __hip_atomic_load(p, __ATOMIC_RELAXED, __HIP_MEMORY_SCOPE_SYSTEM);
}
__device__ __forceinline__ void sysst_f1(float* p, float v) {
  __hip_atomic_store(p, v, __ATOMIC_RELAXED, __HIP_MEMORY_SCOPE_SYSTEM);
}
__device__ __forceinline__ float sysld_f1(const float* p) {
  return __hip_atomic_load(p, __ATOMIC_RELAXED, __HIP_MEMORY_SCOPE_SYSTEM);
}

__global__ __launch_bounds__(256)
void k_init(const float* __restrict__ W1, const float* __restrict__ mask,
            const float* __restrict__ x_init, float* __restrict__ ws,
            float* __restrict__ out) {
  int gt = blockIdx.x * 256 + threadIdx.x;
  int stride = gridDim.x * 256;
  for (int i = gt; i < NN * NN; i += stride) ws[WS_WM + i] = W1[i] * mask[i];
  for (int i = gt; i < NB * NN / 2; i += stride) {
    u64 q = ((const u64*)x_init)[i];
    int r = i >> 8, np = i & 255;
    *((u64*)(out + (size_t)r * NT * NN) + np) = q;   // traj[:,0,:]
    sysst_u64((u64*)(ws + WS_YS) + i, q);            // y_stage at MALL
  }
  if (gt < 32 * 32)
    __hip_atomic_store(((unsigned*)(ws + WS_CNT)) + gt, 0u,
                       __ATOMIC_RELAXED, __HIP_MEMORY_SCOPE_SYSTEM);
}

__device__ __forceinline__ void team_release(unsigned* cnt) {
  __syncthreads();   // compiler drains vmcnt(0) before s_barrier
  if (threadIdx.x == 0) atomicAdd(cnt, 1u);
}
__device__ __forceinline__ void team_wait(unsigned* cnt, unsigned target) {
  if (threadIdx.x == 0) {
    while (__hip_atomic_load(cnt, __ATOMIC_RELAXED,
                             __HIP_MEMORY_SCOPE_AGENT) < target)
      __builtin_amdgcn_s_sleep(1);
  }
  __syncthreads();
}

// Stage 8 rows x 512 fp32 (stride NN) from MALL -> split fp16 planes (swz).
__device__ __forceinline__ void stage8(_Float16* __restrict__ pH,
                                       _Float16* __restrict__ pL,
                                       const float* __restrict__ src,
                                       int tid) {
  const int row = tid >> 5;        // 0..7
  const int segq = tid & 31;       // 0..31, 16 floats each
  const u64* s = (const u64*)(src + (size_t)row * NN) + segq * 8;
  u64 tmp[8];
#pragma unroll
  for (int i = 0; i < 8; ++i) tmp[i] = sysld_u64(s + i);
  half8* dH = (half8*)pH;
  half8* dL = (half8*)pL;
#pragma unroll
  for (int q = 0; q < 2; ++q) {
    half8 hv, lv;
#pragma unroll
    for (int e = 0; e < 4; ++e) {
      union { u64 q64; float f[2]; } u; u.q64 = tmp[q * 4 + e];
#pragma unroll
      for (int x = 0; x < 2; ++x) {
        float f = u.f[x]; _Float16 h = (_Float16)f;
        hv[e * 2 + x] = h;
        lv[e * 2 + x] = (_Float16)((f - (float)h) * 2048.0f);
      }
    }
    int g = segq * 2 + q;
    int idx = row * 64 + (g ^ row);          // row&7 == row
    dH[idx] = hv; dL[idx] = lv;
  }
}

// Full-K GEMM for this wave's 16x16 tile: res[r] = sum_k y[row][k]*w[col][k]
__device__ __forceinline__ void gemm_tile(const _Float16* yHb, const _Float16* yLb,
                                          const _Float16* wb,
                                          int rc, int kg, int wv, float res[4]) {
  const int swz = rc & 7;
  const half8* pAH = (const half8*)yHb;
  const half8* pAL = (const half8*)yLb;
  const half8* pB  = (const half8*)wb;
  const int bbase = (wv * 16 + rc) * 64;
  f32x4 aH = {0.f, 0.f, 0.f, 0.f};
  f32x4 aL = {0.f, 0.f, 0.f, 0.f};
#pragma unroll
  for (int kt = 0; kt < 16; ++kt) {
    const int gs = (kt * 4 + kg) ^ swz;
    half8 av = pAH[rc * 64 + gs];
    half8 al = pAL[rc * 64 + gs];
    half8 bv = pB[bbase + gs];
    aH = __builtin_amdgcn_mfma_f32_16x16x32_f16(av, bv, aH, 0, 0, 0);
    aL = __builtin_amdgcn_mfma_f32_16x16x32_f16(al, bv, aL, 0, 0, 0);
  }
#pragma unroll
  for (int r = 0; r < 4; ++r) res[r] = aH[r] + aL[r] * (1.0f / 2048.0f);
}

__global__ __launch_bounds__(TPB, 1)
void k_ode(const float* __restrict__ tspan,
           const float* __restrict__ W2g,
           const float* __restrict__ b1,
           const float* __restrict__ b2,
           float* __restrict__ ws,
           float* __restrict__ out) {
  extern __shared__ _Float16 ldsh[];
  _Float16* w1 = ldsh;                 // [64 cols][64 granules half8] 64KB
  _Float16* w2 = ldsh + 32768;         // 64KB
  _Float16* yH = ldsh + 65536;         // [16 rows][64 granules] 16KB (rows 8-15 zero)
  _Float16* yL = ldsh + 73728;         // 16KB

  const int bid = blockIdx.x;
  const int cg = bid & 7, rg = bid >> 3;
  const int r0 = rg * 8, j0 = cg * 64;
  const int tid = threadIdx.x;
  const int lane = tid & 63, wv = tid >> 6;
  const int rc = lane & 15, kg = lane >> 4;
  const int mycol = j0 + wv * 16 + rc;
  const bool act = (kg < 2);           // rows kg*4..+3 valid (<8)

  const float* Wm = ws + WS_WM;
  float* hbuf = ws + WS_H;
  float* ystg = ws + WS_YS;
  unsigned* cnt = ((unsigned*)(ws + WS_CNT)) + rg * 32;

  // --- prologue: weights -> fp16 single planes (swizzled), zero-pad y rows ---
  {
    const int col = tid >> 2;          // 0..63
    const int part = tid & 3;          // 0..3, 16 granules each
    const float* s1 = Wm  + (size_t)(j0 + col) * NN + part * 128;
    const float* s2 = W2g + (size_t)(j0 + col) * NN + part * 128;
    half8* d1 = (half8*)w1;
    half8* d2 = (half8*)w2;
    const int key = col & 7;
#pragma unroll
    for (int i = 0; i < 16; ++i) {
      int g = part * 16 + i;
      int idx = col * 64 + (g ^ key);
      half8 hv;
#pragma unroll
      for (int e = 0; e < 8; ++e) hv[e] = (_Float16)s1[i * 8 + e];
      d1[idx] = hv;
#pragma unroll
      for (int e = 0; e < 8; ++e) hv[e] = (_Float16)s2[i * 8 + e];
      d2[idx] = hv;
    }
    half8 z = {};
    half8* zH = (half8*)yH; half8* zL = (half8*)yL;
    for (int i = tid; i < 512; i += TPB) { zH[512 + i] = z; zL[512 + i] = z; }
  }
  const float b1s = b1[mycol], b2s = b2[mycol];
  __syncthreads();

  unsigned epoch = 0;
  float yb[4], ac[4];
  float res[4];

  for (int t = 0; t < NT - 1; ++t) {
    const float dt = tspan[t + 1] - tspan[t];
#pragma unroll 1
    for (int s = 0; s < 4; ++s) {
      // ---------- phase 1: h = tanh(y . W1^T + b1) ----------
      stage8(yH, yL, ystg + (size_t)r0 * NN, tid);
      if (s == 0 && act) {  // latch exact fp32 y_base for this RK4 step
#pragma unroll
        for (int r = 0; r < 4; ++r)
          yb[r] = sysld_f1(ystg + (size_t)(r0 + kg * 4 + r) * NN + mycol);
      }
      __syncthreads();

      gemm_tile(yH, yL, w1, rc, kg, wv, res);
      if (act) {
#pragma unroll
        for (int r = 0; r < 4; ++r)
          sysst_f1(hbuf + (size_t)(r0 + kg * 4 + r) * NN + mycol,
                   tanhf(res[r] + b1s));
      }
      team_release(cnt); ++epoch;
      team_wait(cnt, NTEAM * epoch);

      // ---------- phase 2: k = h . W2^T + b2, RK4 combine ----------
      stage8(yH, yL, hbuf + (size_t)r0 * NN, tid);
      __syncthreads();

      gemm_tile(yH, yL, w2, rc, kg, wv, res);
      if (act) {
#pragma unroll
        for (int r = 0; r < 4; ++r) {
          float k = res[r] + b2s;
          float yn;
          if (s == 0)      { ac[r] = k;          yn = yb[r] + (dt * k) * 0.5f; }
          else if (s == 1) { ac[r] += 2.f * k;   yn = yb[r] + (dt * k) * 0.5f; }
          else if (s == 2) { ac[r] += 2.f * k;   yn = yb[r] + dt * k; }
          else {
            ac[r] += k;
            yn = yb[r] + (dt / 6.0f) * ac[r];
            out[((size_t)(r0 + kg * 4 + r) * NT + (t + 1)) * NN + mycol] = yn;
          }
          sysst_f1(ystg + (size_t)(r0 + kg * 4 + r) * NN + mycol, yn);
        }
      }
      team_release(cnt); ++epoch;
      team_wait(cnt, NTEAM * epoch);
    }
  }
}

extern "C" void kernel_launch(void* const* d_in, const int* in_sizes, int n_in,
                              void* d_out, int out_size, void* d_ws, size_t ws_size,
                              hipStream_t stream) {
  const float* x_init = (const float*)d_in[0];
  const float* tspan  = (const float*)d_in[1];
  const float* W1     = (const float*)d_in[2];
  const float* b1     = (const float*)d_in[3];
  const float* W2     = (const float*)d_in[4];
  const float* b2     = (const float*)d_in[5];
  const float* mask   = (const float*)d_in[6];
  float* out = (float*)d_out;
  float* ws  = (float*)d_ws;

  hipLaunchKernelGGL(k_init, dim3(256), dim3(256), 0, stream,
                     W1, mask, x_init, ws, out);

  const unsigned ldsBytes = 160 * 1024;  // w1 64K + w2 64K + yH 16K + yL 16K
  (void)hipFuncSetAttribute((const void*)k_ode,
                            hipFuncAttributeMaxDynamicSharedMemorySize,
                            (int)ldsBytes);

  // Plain launch: 160KB LDS forces 1 block/CU; grid 256 == CU count, so all
  // blocks are co-resident by capacity — spin barrier is safe.
  hipLaunchKernelGGL(k_ode, dim3(256), dim3(TPB), ldsBytes, stream,
                     tspan, W2, b1, b2, ws, out);
}